// Round 9
// baseline (138.070 us; speedup 1.0000x reference)
//
#include <hip/hip_runtime.h>
#include <hip/hip_bf16.h>
#include <math.h>

#define BB 4
#define NN 4096
#define MM 4096
#define JC 64           // j-chunks (grid.y)
#define CHUNK (MM / JC) // 64 j per block, staged once
#define RR 4            // rows per thread

#define INVF  70.71067811865475f   // 1/(sqrt(2)*blur)
#define IB2   10000.0f             // 1/blur^2
#define INV2  5000.0f              // INVF^2
#define LOG2E 1.4426950408889634f
#define SCY   (INVF * 2.0f * LOG2E) // yy-side scale (log2 domain)

// ws layout in floats
#define PART_F 0                          // BB*JC*NN*4 floats = 4194304
#define BLK_F  (BB * JC * NN * 4)         // 64*23 doubles

typedef __attribute__((ext_vector_type(2))) float f32x2;

// Forced VOP3P packed-f32 ops (compiler scalarizes elementwise builtins)
static __device__ __forceinline__ f32x2 pkfma(f32x2 a, f32x2 b, f32x2 c) {
  f32x2 d;
  asm("v_pk_fma_f32 %0, %1, %2, %3" : "=v"(d) : "v"(a), "v"(b), "v"(c));
  return d;
}
static __device__ __forceinline__ f32x2 pkmul(f32x2 a, f32x2 b) {
  f32x2 d;
  asm("v_pk_mul_f32 %0, %1, %2" : "=v"(d) : "v"(a), "v"(b));
  return d;
}
static __device__ __forceinline__ f32x2 pkadd(f32x2 a, f32x2 b) {
  f32x2 d;
  asm("v_pk_add_f32 %0, %1, %2" : "=v"(d) : "v"(a), "v"(b));
  return d;
}

// ---------------------------------------------------------------- attention
__global__ __launch_bounds__(256, 2) void attn_kernel(
    const float* __restrict__ src_fea, const float* __restrict__ tgt_fea,
    const float* __restrict__ G_j, const float* __restrict__ tgt,
    float* __restrict__ partial) {
  __shared__ float  yyt[CHUNK][16];
  __shared__ float4 tg4s[CHUNK];
  int tid = threadIdx.x;
  int b = blockIdx.z, jc = blockIdx.y;
  int j0 = b * MM + jc * CHUNK;

  // ---- stage chunk: 4 threads per j-row (scale SCY; gyl via 4-lane shfl)
  {
    int jl = tid >> 2, part = tid & 3;
    int jg = j0 + jl;
    float4 v = *((const float4*)(tgt_fea + (size_t)jg * 16) + part);
    float ss = v.x*v.x + v.y*v.y + v.z*v.z + v.w*v.w;
    ss += __shfl_xor(ss, 1, 64);
    ss += __shfl_xor(ss, 2, 64);
    ((float4*)yyt[jl])[part] =
        make_float4(v.x * SCY, v.y * SCY, v.z * SCY, v.w * SCY);
    if (part == 0) {
      float y2n = ss * INV2;                    // ||yy||^2 in nats
      float gyl = LOG2E * (G_j[jg] * IB2 - y2n);
      tg4s[jl] = make_float4(tgt[(size_t)jg * 3 + 0],
                             tgt[(size_t)jg * 3 + 1],
                             tgt[(size_t)jg * 3 + 2], gyl);
    }
  }

  // ---- RR query rows in registers as f32x2 pairs, scaled INVF
  int ib = blockIdx.x * (256 * RR) + tid;      // rows: ib + 256*r
  f32x2 q2[RR][8];
  #pragma unroll
  for (int r = 0; r < RR; ++r) {
    const float4* sf = (const float4*)(src_fea
                     + ((size_t)b * NN + ib + 256 * r) * 16);
    #pragma unroll
    for (int k = 0; k < 4; ++k) {
      float4 v = sf[k];
      q2[r][2*k]   = (f32x2){ v.x * INVF, v.y * INVF };
      q2[r][2*k+1] = (f32x2){ v.z * INVF, v.w * INVF };
    }
  }

  __syncthreads();

  f32x2 t01[RR], t2s[RR];
  #pragma unroll
  for (int r = 0; r < RR; ++r) { t01[r] = (f32x2){0.f,0.f}; t2s[r] = (f32x2){0.f,0.f}; }

  #pragma unroll 4
  for (int jj = 0; jj < CHUNK; ++jj) {
    const float4* yr = (const float4*)yyt[jj];
    float4 ya = yr[0], yb = yr[1], yc = yr[2], yd = yr[3];
    float4 tg = tg4s[jj];                       // tg.w = gyl (log2 bias)
    f32x2 yv0 = (f32x2){ya.x, ya.y}, yv1 = (f32x2){ya.z, ya.w};
    f32x2 yv2 = (f32x2){yb.x, yb.y}, yv3 = (f32x2){yb.z, yb.w};
    f32x2 yv4 = (f32x2){yc.x, yc.y}, yv5 = (f32x2){yc.z, yc.w};
    f32x2 yv6 = (f32x2){yd.x, yd.y}, yv7 = (f32x2){yd.z, yd.w};
    f32x2 bias = (f32x2){tg.w, 0.f};
    f32x2 tgxy = (f32x2){tg.x, tg.y};
    f32x2 tgz1 = (f32x2){tg.z, 1.f};
    #pragma unroll
    for (int r = 0; r < RR; ++r) {
      f32x2 cA = pkfma(q2[r][0], yv0, bias);
      cA = pkfma(q2[r][2], yv2, cA);
      cA = pkfma(q2[r][4], yv4, cA);
      cA = pkfma(q2[r][6], yv6, cA);
      f32x2 cB = pkmul(q2[r][1], yv1);
      cB = pkfma(q2[r][3], yv3, cB);
      cB = pkfma(q2[r][5], yv5, cB);
      cB = pkfma(q2[r][7], yv7, cB);
      f32x2 cs = pkadd(cA, cB);
      float p = __builtin_amdgcn_exp2f(cs.x + cs.y);
      f32x2 pp2 = (f32x2){p, p};
      t01[r] = pkfma(pp2, tgxy, t01[r]);
      t2s[r] = pkfma(pp2, tgz1, t2s[r]);
    }
  }

  float4* pp = (float4*)partial + (size_t)(b * JC + jc) * NN;
  #pragma unroll
  for (int r = 0; r < RR; ++r)
    pp[ib + 256 * r] = make_float4(t01[r].x, t01[r].y, t2s[r].x, t2s[r].y);
}

// ---------------------------------------------------------------- combine (one thread per row)
__global__ __launch_bounds__(256) void combine_kernel(
    const float* __restrict__ partial, const float* __restrict__ src_fea,
    const float* __restrict__ src, const float* __restrict__ F_i,
    double* __restrict__ blockpart) {
  int b = blockIdx.x, xb = blockIdx.y, tid = threadIdx.x;
  int i = xb * 256 + tid;
  int g = b * NN + i;

  float S = 0.f, T0 = 0.f, T1 = 0.f, T2 = 0.f;
  #pragma unroll 8
  for (int c = 0; c < JC; ++c) {
    float4 v = ((const float4*)partial)[(size_t)(b * JC + c) * NN + i];
    T0 += v.x; T1 += v.y; T2 += v.z; S += v.w;
  }
  float invS = 1.f / S;
  float y0 = T0 * invS, y1 = T1 * invS, y2 = T2 * invS;

  const float4* sfp = (const float4*)src_fea + (size_t)g * 4;
  float ss = 0.f;
  #pragma unroll
  for (int k = 0; k < 4; ++k) {
    float4 a = sfp[k];
    ss += a.x*a.x + a.y*a.y + a.z*a.z + a.w*a.w;
  }
  float x2 = ss * INV2;
  // w = exp(f'-x2)*S ; log2-domain: exp2((f'-x2)*log2e + log2 S)
  float w = __builtin_amdgcn_exp2f((F_i[g] * IB2 - x2) * LOG2E
                                   + __builtin_amdgcn_logf(S));

  float px = src[(size_t)g * 3 + 0];
  float py = src[(size_t)g * 3 + 1];
  float pz = src[(size_t)g * 3 + 2];

  double acc[23];
  double wd = (double)w, w2 = wd * wd;
  acc[0]  = wd;
  acc[1]  = wd * px;  acc[2]  = wd * py;  acc[3]  = wd * pz;
  acc[4]  = wd * y0;  acc[5]  = wd * y1;  acc[6]  = wd * y2;
  acc[7]  = w2;
  acc[8]  = w2 * px;  acc[9]  = w2 * py;  acc[10] = w2 * pz;
  acc[11] = w2 * y0;  acc[12] = w2 * y1;  acc[13] = w2 * y2;
  acc[14] = w2 * y0 * px; acc[15] = w2 * y0 * py; acc[16] = w2 * y0 * pz;
  acc[17] = w2 * y1 * px; acc[18] = w2 * y1 * py; acc[19] = w2 * y1 * pz;
  acc[20] = w2 * y2 * px; acc[21] = w2 * y2 * py; acc[22] = w2 * y2 * pz;

  #pragma unroll
  for (int k = 0; k < 23; ++k) {
    #pragma unroll
    for (int off = 32; off > 0; off >>= 1)
      acc[k] += __shfl_down(acc[k], off, 64);
  }
  __shared__ double red[4][23];
  int wave = tid >> 6, lane = tid & 63;
  if (lane == 0) {
    #pragma unroll
    for (int k = 0; k < 23; ++k) red[wave][k] = acc[k];
  }
  __syncthreads();
  if (tid < 23) {
    double s = red[0][tid] + red[1][tid] + red[2][tid] + red[3][tid];
    blockpart[((size_t)b * 16 + xb) * 23 + tid] = s;
  }
}

// ---------------------------------------------------------------- finalize (SVD)
__device__ __forceinline__ double det3(const double M[3][3]) {
  return M[0][0] * (M[1][1] * M[2][2] - M[1][2] * M[2][1])
       - M[0][1] * (M[1][0] * M[2][2] - M[1][2] * M[2][0])
       + M[0][2] * (M[1][0] * M[2][1] - M[1][1] * M[2][0]);
}

__global__ void finalize_kernel(const double* __restrict__ blockpart,
                                float* __restrict__ out) {
  __shared__ double sm[BB][23];
  int tid = threadIdx.x;
  int b = tid >> 6, lane = tid & 63;
  if (lane < 23) {
    double s = 0.0;
    for (int xb = 0; xb < 16; ++xb)
      s += blockpart[((size_t)b * 16 + xb) * 23 + lane];
    sm[b][lane] = s;
  }
  __syncthreads();
  if (lane != 0) return;

  double mo[23];
  #pragma unroll
  for (int k = 0; k < 23; ++k) mo[k] = sm[b][k];

  double sw = mo[0];
  double mux[3] = { mo[1] / sw, mo[2] / sw, mo[3] / sw };
  double muy[3] = { mo[4] / sw, mo[5] / sw, mo[6] / sw };
  double sw2 = mo[7];
  double A[3][3];
  for (int d = 0; d < 3; ++d)
    for (int e = 0; e < 3; ++e)
      A[d][e] = mo[14 + d * 3 + e] - muy[d] * mo[8 + e] - mux[e] * mo[11 + d]
              + sw2 * muy[d] * mux[e];

  double ATA[3][3];
  for (int p = 0; p < 3; ++p)
    for (int q = 0; q < 3; ++q)
      ATA[p][q] = A[0][p] * A[0][q] + A[1][p] * A[1][q] + A[2][p] * A[2][q];

  double V[3][3] = { {1,0,0}, {0,1,0}, {0,0,1} };
  for (int sweep = 0; sweep < 8; ++sweep) {
    for (int pair = 0; pair < 3; ++pair) {
      int p = (pair == 2) ? 1 : 0;
      int q = (pair == 0) ? 1 : 2;
      double apq = ATA[p][q];
      if (fabs(apq) < 1e-300) continue;
      double tau = (ATA[q][q] - ATA[p][p]) / (2.0 * apq);
      double tt = ((tau >= 0.0) ? 1.0 : -1.0) / (fabs(tau) + sqrt(1.0 + tau * tau));
      double c = 1.0 / sqrt(1.0 + tt * tt), sn = tt * c;
      for (int k = 0; k < 3; ++k) {
        double akp = ATA[k][p], akq = ATA[k][q];
        ATA[k][p] = c * akp - sn * akq;
        ATA[k][q] = sn * akp + c * akq;
      }
      for (int k = 0; k < 3; ++k) {
        double apk = ATA[p][k], aqk = ATA[q][k];
        ATA[p][k] = c * apk - sn * aqk;
        ATA[q][k] = sn * apk + c * aqk;
      }
      for (int k = 0; k < 3; ++k) {
        double vkp = V[k][p], vkq = V[k][q];
        V[k][p] = c * vkp - sn * vkq;
        V[k][q] = sn * vkp + c * vkq;
      }
    }
  }

  double U[3][3];
  for (int k = 0; k < 3; ++k) {
    double sv = sqrt(fmax(ATA[k][k], 0.0));
    double u0 = A[0][0] * V[0][k] + A[0][1] * V[1][k] + A[0][2] * V[2][k];
    double u1 = A[1][0] * V[0][k] + A[1][1] * V[1][k] + A[1][2] * V[2][k];
    double u2 = A[2][0] * V[0][k] + A[2][1] * V[1][k] + A[2][2] * V[2][k];
    double inv = (sv > 1e-300) ? 1.0 / sv : 0.0;
    U[0][k] = u0 * inv; U[1][k] = u1 * inv; U[2][k] = u2 * inv;
  }

  double dd = det3(U) * det3(V);
  double R[3][3];
  for (int d = 0; d < 3; ++d)
    for (int e = 0; e < 3; ++e)
      R[d][e] = U[d][0] * V[e][0] + U[d][1] * V[e][1] + U[d][2] * V[e][2];
  R[2][0] *= dd; R[2][1] *= dd; R[2][2] *= dd;

  double tr[3];
  for (int d = 0; d < 3; ++d)
    tr[d] = muy[d] - (R[d][0] * mux[0] + R[d][1] * mux[1] + R[d][2] * mux[2]);

  for (int d = 0; d < 3; ++d)
    for (int e = 0; e < 3; ++e)
      out[b * 9 + d * 3 + e] = (float)R[d][e];
  out[BB * 9 + b * 3 + 0] = (float)tr[0];
  out[BB * 9 + b * 3 + 1] = (float)tr[1];
  out[BB * 9 + b * 3 + 2] = (float)tr[2];
}

// ---------------------------------------------------------------- launch
extern "C" void kernel_launch(void* const* d_in, const int* in_sizes, int n_in,
                              void* d_out, int out_size, void* d_ws, size_t ws_size,
                              hipStream_t stream) {
  const float* src     = (const float*)d_in[0];
  const float* tgt     = (const float*)d_in[1];
  const float* src_fea = (const float*)d_in[2];
  const float* tgt_fea = (const float*)d_in[3];
  const float* F_i     = (const float*)d_in[4];
  const float* G_j     = (const float*)d_in[5];
  float* ws  = (float*)d_ws;
  float* out = (float*)d_out;
  double* blockpart = (double*)(ws + BLK_F);

  dim3 grid(NN / (256 * RR), JC, BB);   // 4 x 64 x 4 = 1024 blocks
  attn_kernel<<<grid, 256, 0, stream>>>(src_fea, tgt_fea, G_j, tgt, ws + PART_F);
  dim3 cgrid(BB, NN / 256);
  combine_kernel<<<cgrid, 256, 0, stream>>>(ws + PART_F, src_fea, src, F_i, blockpart);
  finalize_kernel<<<1, 256, 0, stream>>>(blockpart, out);
}

// Round 10
// 137.017 us; speedup vs baseline: 1.0077x; 1.0077x over previous
//
#include <hip/hip_runtime.h>
#include <hip/hip_bf16.h>
#include <math.h>

#define BB 4
#define NN 4096
#define MM 4096
#define JC 64           // j-chunks (grid.y)
#define CHUNK (MM / JC) // 64 j per block, staged once
#define RR 2            // rows per thread (halved: more blocks -> more TLP)

#define INVF  70.71067811865475f   // 1/(sqrt(2)*blur)
#define IB2   10000.0f             // 1/blur^2
#define INV2  5000.0f              // INVF^2
#define LOG2E 1.4426950408889634f
#define SCY   (INVF * 2.0f * LOG2E) // yy-side scale (log2 domain)

// ws layout in floats
#define PART_F 0                          // BB*JC*NN*4 floats = 4194304
#define BLK_F  (BB * JC * NN * 4)         // 64*23 doubles

typedef __attribute__((ext_vector_type(2))) float f32x2;

// Packed f32 ops (VOP3P). Note: on gfx950 these are issue-slot savers only —
// the 32-wide FMA units still spend 4 cy/wave-op — but fewer slots frees the
// scheduler to interleave more waves.
static __device__ __forceinline__ f32x2 pkfma(f32x2 a, f32x2 b, f32x2 c) {
  f32x2 d;
  asm("v_pk_fma_f32 %0, %1, %2, %3" : "=v"(d) : "v"(a), "v"(b), "v"(c));
  return d;
}
static __device__ __forceinline__ f32x2 pkmul(f32x2 a, f32x2 b) {
  f32x2 d;
  asm("v_pk_mul_f32 %0, %1, %2" : "=v"(d) : "v"(a), "v"(b));
  return d;
}
static __device__ __forceinline__ f32x2 pkadd(f32x2 a, f32x2 b) {
  f32x2 d;
  asm("v_pk_add_f32 %0, %1, %2" : "=v"(d) : "v"(a), "v"(b));
  return d;
}

// ---------------------------------------------------------------- attention
__global__ __launch_bounds__(256, 4) void attn_kernel(
    const float* __restrict__ src_fea, const float* __restrict__ tgt_fea,
    const float* __restrict__ G_j, const float* __restrict__ tgt,
    float* __restrict__ partial) {
  __shared__ float  yyt[CHUNK][16];
  __shared__ float4 tg4s[CHUNK];
  int tid = threadIdx.x;
  int b = blockIdx.z, jc = blockIdx.y;
  int j0 = b * MM + jc * CHUNK;

  // ---- stage chunk: 4 threads per j-row (scale SCY; gyl via 4-lane shfl)
  {
    int jl = tid >> 2, part = tid & 3;
    int jg = j0 + jl;
    float4 v = *((const float4*)(tgt_fea + (size_t)jg * 16) + part);
    float ss = v.x*v.x + v.y*v.y + v.z*v.z + v.w*v.w;
    ss += __shfl_xor(ss, 1, 64);
    ss += __shfl_xor(ss, 2, 64);
    ((float4*)yyt[jl])[part] =
        make_float4(v.x * SCY, v.y * SCY, v.z * SCY, v.w * SCY);
    if (part == 0) {
      float y2n = ss * INV2;                    // ||yy||^2 in nats
      float gyl = LOG2E * (G_j[jg] * IB2 - y2n);
      tg4s[jl] = make_float4(tgt[(size_t)jg * 3 + 0],
                             tgt[(size_t)jg * 3 + 1],
                             tgt[(size_t)jg * 3 + 2], gyl);
    }
  }

  // ---- RR query rows in registers as f32x2 pairs, scaled INVF
  int ib = blockIdx.x * (256 * RR) + tid;      // rows: ib + 256*r
  f32x2 q2[RR][8];
  #pragma unroll
  for (int r = 0; r < RR; ++r) {
    const float4* sf = (const float4*)(src_fea
                     + ((size_t)b * NN + ib + 256 * r) * 16);
    #pragma unroll
    for (int k = 0; k < 4; ++k) {
      float4 v = sf[k];
      q2[r][2*k]   = (f32x2){ v.x * INVF, v.y * INVF };
      q2[r][2*k+1] = (f32x2){ v.z * INVF, v.w * INVF };
    }
  }

  __syncthreads();

  f32x2 t01[RR], t2s[RR];
  #pragma unroll
  for (int r = 0; r < RR; ++r) { t01[r] = (f32x2){0.f,0.f}; t2s[r] = (f32x2){0.f,0.f}; }

  #pragma unroll 4
  for (int jj = 0; jj < CHUNK; ++jj) {
    const float4* yr = (const float4*)yyt[jj];
    float4 ya = yr[0], yb = yr[1], yc = yr[2], yd = yr[3];
    float4 tg = tg4s[jj];                       // tg.w = gyl (log2 bias)
    f32x2 yv0 = (f32x2){ya.x, ya.y}, yv1 = (f32x2){ya.z, ya.w};
    f32x2 yv2 = (f32x2){yb.x, yb.y}, yv3 = (f32x2){yb.z, yb.w};
    f32x2 yv4 = (f32x2){yc.x, yc.y}, yv5 = (f32x2){yc.z, yc.w};
    f32x2 yv6 = (f32x2){yd.x, yd.y}, yv7 = (f32x2){yd.z, yd.w};
    f32x2 bias = (f32x2){tg.w, 0.f};
    f32x2 tgxy = (f32x2){tg.x, tg.y};
    f32x2 tgz1 = (f32x2){tg.z, 1.f};
    #pragma unroll
    for (int r = 0; r < RR; ++r) {
      f32x2 cA = pkfma(q2[r][0], yv0, bias);
      cA = pkfma(q2[r][2], yv2, cA);
      cA = pkfma(q2[r][4], yv4, cA);
      cA = pkfma(q2[r][6], yv6, cA);
      f32x2 cB = pkmul(q2[r][1], yv1);
      cB = pkfma(q2[r][3], yv3, cB);
      cB = pkfma(q2[r][5], yv5, cB);
      cB = pkfma(q2[r][7], yv7, cB);
      f32x2 cs = pkadd(cA, cB);
      float p = __builtin_amdgcn_exp2f(cs.x + cs.y);
      f32x2 pp2 = (f32x2){p, p};
      t01[r] = pkfma(pp2, tgxy, t01[r]);
      t2s[r] = pkfma(pp2, tgz1, t2s[r]);
    }
  }

  float4* pp = (float4*)partial + (size_t)(b * JC + jc) * NN;
  #pragma unroll
  for (int r = 0; r < RR; ++r)
    pp[ib + 256 * r] = make_float4(t01[r].x, t01[r].y, t2s[r].x, t2s[r].y);
}

// ---------------------------------------------------------------- combine (one thread per row)
__global__ __launch_bounds__(256) void combine_kernel(
    const float* __restrict__ partial, const float* __restrict__ src_fea,
    const float* __restrict__ src, const float* __restrict__ F_i,
    double* __restrict__ blockpart) {
  int b = blockIdx.x, xb = blockIdx.y, tid = threadIdx.x;
  int i = xb * 256 + tid;
  int g = b * NN + i;

  float S = 0.f, T0 = 0.f, T1 = 0.f, T2 = 0.f;
  #pragma unroll 8
  for (int c = 0; c < JC; ++c) {
    float4 v = ((const float4*)partial)[(size_t)(b * JC + c) * NN + i];
    T0 += v.x; T1 += v.y; T2 += v.z; S += v.w;
  }
  float invS = 1.f / S;
  float y0 = T0 * invS, y1 = T1 * invS, y2 = T2 * invS;

  const float4* sfp = (const float4*)src_fea + (size_t)g * 4;
  float ss = 0.f;
  #pragma unroll
  for (int k = 0; k < 4; ++k) {
    float4 a = sfp[k];
    ss += a.x*a.x + a.y*a.y + a.z*a.z + a.w*a.w;
  }
  float x2 = ss * INV2;
  // w = exp(f'-x2)*S ; log2-domain: exp2((f'-x2)*log2e + log2 S)
  float w = __builtin_amdgcn_exp2f((F_i[g] * IB2 - x2) * LOG2E
                                   + __builtin_amdgcn_logf(S));

  float px = src[(size_t)g * 3 + 0];
  float py = src[(size_t)g * 3 + 1];
  float pz = src[(size_t)g * 3 + 2];

  double acc[23];
  double wd = (double)w, w2 = wd * wd;
  acc[0]  = wd;
  acc[1]  = wd * px;  acc[2]  = wd * py;  acc[3]  = wd * pz;
  acc[4]  = wd * y0;  acc[5]  = wd * y1;  acc[6]  = wd * y2;
  acc[7]  = w2;
  acc[8]  = w2 * px;  acc[9]  = w2 * py;  acc[10] = w2 * pz;
  acc[11] = w2 * y0;  acc[12] = w2 * y1;  acc[13] = w2 * y2;
  acc[14] = w2 * y0 * px; acc[15] = w2 * y0 * py; acc[16] = w2 * y0 * pz;
  acc[17] = w2 * y1 * px; acc[18] = w2 * y1 * py; acc[19] = w2 * y1 * pz;
  acc[20] = w2 * y2 * px; acc[21] = w2 * y2 * py; acc[22] = w2 * y2 * pz;

  #pragma unroll
  for (int k = 0; k < 23; ++k) {
    #pragma unroll
    for (int off = 32; off > 0; off >>= 1)
      acc[k] += __shfl_down(acc[k], off, 64);
  }
  __shared__ double red[4][23];
  int wave = tid >> 6, lane = tid & 63;
  if (lane == 0) {
    #pragma unroll
    for (int k = 0; k < 23; ++k) red[wave][k] = acc[k];
  }
  __syncthreads();
  if (tid < 23) {
    double s = red[0][tid] + red[1][tid] + red[2][tid] + red[3][tid];
    blockpart[((size_t)b * 16 + xb) * 23 + tid] = s;
  }
}

// ---------------------------------------------------------------- finalize (SVD)
__device__ __forceinline__ double det3(const double M[3][3]) {
  return M[0][0] * (M[1][1] * M[2][2] - M[1][2] * M[2][1])
       - M[0][1] * (M[1][0] * M[2][2] - M[1][2] * M[2][0])
       + M[0][2] * (M[1][0] * M[2][1] - M[1][1] * M[2][0]);
}

__global__ void finalize_kernel(const double* __restrict__ blockpart,
                                float* __restrict__ out) {
  __shared__ double sm[BB][23];
  int tid = threadIdx.x;
  int b = tid >> 6, lane = tid & 63;
  if (lane < 23) {
    double s = 0.0;
    for (int xb = 0; xb < 16; ++xb)
      s += blockpart[((size_t)b * 16 + xb) * 23 + lane];
    sm[b][lane] = s;
  }
  __syncthreads();
  if (lane != 0) return;

  double mo[23];
  #pragma unroll
  for (int k = 0; k < 23; ++k) mo[k] = sm[b][k];

  double sw = mo[0];
  double mux[3] = { mo[1] / sw, mo[2] / sw, mo[3] / sw };
  double muy[3] = { mo[4] / sw, mo[5] / sw, mo[6] / sw };
  double sw2 = mo[7];
  double A[3][3];
  for (int d = 0; d < 3; ++d)
    for (int e = 0; e < 3; ++e)
      A[d][e] = mo[14 + d * 3 + e] - muy[d] * mo[8 + e] - mux[e] * mo[11 + d]
              + sw2 * muy[d] * mux[e];

  double ATA[3][3];
  for (int p = 0; p < 3; ++p)
    for (int q = 0; q < 3; ++q)
      ATA[p][q] = A[0][p] * A[0][q] + A[1][p] * A[1][q] + A[2][p] * A[2][q];

  double V[3][3] = { {1,0,0}, {0,1,0}, {0,0,1} };
  for (int sweep = 0; sweep < 8; ++sweep) {
    for (int pair = 0; pair < 3; ++pair) {
      int p = (pair == 2) ? 1 : 0;
      int q = (pair == 0) ? 1 : 2;
      double apq = ATA[p][q];
      if (fabs(apq) < 1e-300) continue;
      double tau = (ATA[q][q] - ATA[p][p]) / (2.0 * apq);
      double tt = ((tau >= 0.0) ? 1.0 : -1.0) / (fabs(tau) + sqrt(1.0 + tau * tau));
      double c = 1.0 / sqrt(1.0 + tt * tt), sn = tt * c;
      for (int k = 0; k < 3; ++k) {
        double akp = ATA[k][p], akq = ATA[k][q];
        ATA[k][p] = c * akp - sn * akq;
        ATA[k][q] = sn * akp + c * akq;
      }
      for (int k = 0; k < 3; ++k) {
        double apk = ATA[p][k], aqk = ATA[q][k];
        ATA[p][k] = c * apk - sn * aqk;
        ATA[q][k] = sn * apk + c * aqk;
      }
      for (int k = 0; k < 3; ++k) {
        double vkp = V[k][p], vkq = V[k][q];
        V[k][p] = c * vkp - sn * vkq;
        V[k][q] = sn * vkp + c * vkq;
      }
    }
  }

  double U[3][3];
  for (int k = 0; k < 3; ++k) {
    double sv = sqrt(fmax(ATA[k][k], 0.0));
    double u0 = A[0][0] * V[0][k] + A[0][1] * V[1][k] + A[0][2] * V[2][k];
    double u1 = A[1][0] * V[0][k] + A[1][1] * V[1][k] + A[1][2] * V[2][k];
    double u2 = A[2][0] * V[0][k] + A[2][1] * V[1][k] + A[2][2] * V[2][k];
    double inv = (sv > 1e-300) ? 1.0 / sv : 0.0;
    U[0][k] = u0 * inv; U[1][k] = u1 * inv; U[2][k] = u2 * inv;
  }

  double dd = det3(U) * det3(V);
  double R[3][3];
  for (int d = 0; d < 3; ++d)
    for (int e = 0; e < 3; ++e)
      R[d][e] = U[d][0] * V[e][0] + U[d][1] * V[e][1] + U[d][2] * V[e][2];
  R[2][0] *= dd; R[2][1] *= dd; R[2][2] *= dd;

  double tr[3];
  for (int d = 0; d < 3; ++d)
    tr[d] = muy[d] - (R[d][0] * mux[0] + R[d][1] * mux[1] + R[d][2] * mux[2]);

  for (int d = 0; d < 3; ++d)
    for (int e = 0; e < 3; ++e)
      out[b * 9 + d * 3 + e] = (float)R[d][e];
  out[BB * 9 + b * 3 + 0] = (float)tr[0];
  out[BB * 9 + b * 3 + 1] = (float)tr[1];
  out[BB * 9 + b * 3 + 2] = (float)tr[2];
}

// ---------------------------------------------------------------- launch
extern "C" void kernel_launch(void* const* d_in, const int* in_sizes, int n_in,
                              void* d_out, int out_size, void* d_ws, size_t ws_size,
                              hipStream_t stream) {
  const float* src     = (const float*)d_in[0];
  const float* tgt     = (const float*)d_in[1];
  const float* src_fea = (const float*)d_in[2];
  const float* tgt_fea = (const float*)d_in[3];
  const float* F_i     = (const float*)d_in[4];
  const float* G_j     = (const float*)d_in[5];
  float* ws  = (float*)d_ws;
  float* out = (float*)d_out;
  double* blockpart = (double*)(ws + BLK_F);

  dim3 grid(NN / (256 * RR), JC, BB);   // 8 x 64 x 4 = 2048 blocks
  attn_kernel<<<grid, 256, 0, stream>>>(src_fea, tgt_fea, G_j, tgt, ws + PART_F);
  dim3 cgrid(BB, NN / 256);
  combine_kernel<<<cgrid, 256, 0, stream>>>(ws + PART_F, src_fea, src, F_i, blockpart);
  finalize_kernel<<<1, 256, 0, stream>>>(blockpart, out);
}

// Round 11
// 128.955 us; speedup vs baseline: 1.0707x; 1.0625x over previous
//
#include <hip/hip_runtime.h>
#include <hip/hip_bf16.h>
#include <math.h>

#define BB 4
#define NN 4096
#define MM 4096
#define JC 64           // j-chunks (grid.y); CHUNK = 64 j = 2 MFMA j-tiles
#define CHUNK (MM / JC)

#define INVF  70.71067811865475f   // 1/(sqrt(2)*blur)
#define IB2   10000.0f             // 1/blur^2
#define INV2  5000.0f              // INVF^2
#define LOG2E 1.4426950408889634f
#define SCY   (INVF * 2.0f * LOG2E) // yy-side scale (log2 domain)

// ws layout in floats
#define YF_F   0                          // BB*(MM/32)*128 uint4 = 262144 floats (split bf16 A-frags)
#define TG4_F  262144                     // BB*MM float4 = 65536 floats (tgt.xyz, gyl)
#define PART_F 327680                     // BB*JC*NN*4 = 4194304 floats
#define BLK_F  (PART_F + BB * JC * NN * 4) // 64*23 doubles

typedef __attribute__((ext_vector_type(2)))  float f32x2;
typedef __attribute__((ext_vector_type(8)))  short short8v;
typedef __attribute__((ext_vector_type(16))) float f32x16;

static __device__ __forceinline__ unsigned short f2bf(float x) {
  unsigned int u = __builtin_bit_cast(unsigned int, x);
  u += 0x7fffu + ((u >> 16) & 1u);   // RNE
  return (unsigned short)(u >> 16);
}
static __device__ __forceinline__ float bf2f(unsigned short h) {
  unsigned int u = ((unsigned int)h) << 16;
  return __builtin_bit_cast(float, u);
}
// split v into hi+lo bf16 (Ootomo): v ≈ bf2f(h) + bf2f(l), error ~2^-18 |v|
static __device__ __forceinline__ void splitbf(float v, unsigned short& h, unsigned short& l) {
  h = f2bf(v);
  l = f2bf(v - bf2f(h));
}
static __device__ __forceinline__ f32x2 pkfma(f32x2 a, f32x2 b, f32x2 c) {
  f32x2 d;
  asm("v_pk_fma_f32 %0, %1, %2, %3" : "=v"(d) : "v"(a), "v"(b), "v"(c));
  return d;
}

// ---------------------------------------------------------------- prep: split-bf16 A-frags + tgt records
// A-frag k-map convention (shared by A and B → permutation-proof):
//   lane(h=l>>5, row=j&31): words 0,1 = feats[4h..4h+3], words 2,3 = feats[8+4h..8+4h+3]
// ws YF layout per 32-j tile: [part(hi=0,lo=1)][lane(64)] uint4, tiles sequential (128 uint4/tile)
__global__ __launch_bounds__(256) void prep_kernel(
    const float* __restrict__ tgt_fea, const float* __restrict__ G_j,
    const float* __restrict__ tgt, float* __restrict__ ws) {
  int idx = blockIdx.x * 256 + threadIdx.x; // [0, BB*MM)
  int b = idx >> 12, j = idx & (MM - 1);
  const float4* tf = (const float4*)(tgt_fea + (size_t)idx * 16);
  float f[16];
  float ss = 0.f;
  #pragma unroll
  for (int k = 0; k < 4; ++k) {
    float4 v = tf[k];
    f[4*k+0] = v.x; f[4*k+1] = v.y; f[4*k+2] = v.z; f[4*k+3] = v.w;
    ss += v.x*v.x + v.y*v.y + v.z*v.z + v.w*v.w;
  }
  float y2n = ss * INV2;   // ||yy||^2 in nats

  unsigned short vh[16], vl[16];
  #pragma unroll
  for (int k = 0; k < 16; ++k) splitbf(f[k] * SCY, vh[k], vl[k]);

  uint4* base = (uint4*)(ws + YF_F) + ((size_t)b * (MM/32) + (j >> 5)) * 128;
  int ll = j & 31, lh = 32 + (j & 31);
  // lo-half lane entries (k-set {0..3, 8..11})
  base[0*64 + ll] = make_uint4(
      (unsigned)vh[0] | ((unsigned)vh[1] << 16), (unsigned)vh[2] | ((unsigned)vh[3] << 16),
      (unsigned)vh[8] | ((unsigned)vh[9] << 16), (unsigned)vh[10] | ((unsigned)vh[11] << 16));
  base[1*64 + ll] = make_uint4(
      (unsigned)vl[0] | ((unsigned)vl[1] << 16), (unsigned)vl[2] | ((unsigned)vl[3] << 16),
      (unsigned)vl[8] | ((unsigned)vl[9] << 16), (unsigned)vl[10] | ((unsigned)vl[11] << 16));
  // hi-half lane entries (k-set {4..7, 12..15})
  base[0*64 + lh] = make_uint4(
      (unsigned)vh[4] | ((unsigned)vh[5] << 16), (unsigned)vh[6] | ((unsigned)vh[7] << 16),
      (unsigned)vh[12] | ((unsigned)vh[13] << 16), (unsigned)vh[14] | ((unsigned)vh[15] << 16));
  base[1*64 + lh] = make_uint4(
      (unsigned)vl[4] | ((unsigned)vl[5] << 16), (unsigned)vl[6] | ((unsigned)vl[7] << 16),
      (unsigned)vl[12] | ((unsigned)vl[13] << 16), (unsigned)vl[14] | ((unsigned)vl[15] << 16));

  float gyl = LOG2E * (G_j[idx] * IB2 - y2n);
  ((float4*)(ws + TG4_F))[idx] = make_float4(
      tgt[(size_t)idx*3+0], tgt[(size_t)idx*3+1], tgt[(size_t)idx*3+2], gyl);
}

// ---------------------------------------------------------------- attention (split-bf16 MFMA scores, f32 VALU PV)
__global__ __launch_bounds__(256, 4) void attn_kernel(
    const float* __restrict__ src_fea, const float* __restrict__ ws,
    float* __restrict__ partial) {
  __shared__ uint4  sY[256];     // 4 KB: 2 j-tiles x {hi,lo} x 64 lanes
  __shared__ float4 tg4s[CHUNK]; // 1 KB
  int tid = threadIdx.x;
  int w = tid >> 6, l = tid & 63;
  int il = l & 31, h = l >> 5;
  int b = blockIdx.z, jc = blockIdx.y;

  // stage A-frags + tgt records for this chunk
  {
    const uint4* gY = (const uint4*)(ws + YF_F)
                    + ((size_t)b * (MM/32) + jc * 2) * 128;
    sY[tid] = gY[tid];
    if (tid < CHUNK)
      tg4s[tid] = ((const float4*)(ws + TG4_F))[(size_t)b * MM + jc * CHUNK + tid];
  }

  // B-frags (queries): wave handles 2 i-tiles (64 rows); split-bf16, same k-map
  int i0 = blockIdx.x * 256 + w * 64;
  union U { uint4 q; short8v s; };
  U xaH, xaL, xbH, xbL;
  #pragma unroll
  for (int t = 0; t < 2; ++t) {
    const float* sf = src_fea + ((size_t)b * NN + i0 + t * 32 + il) * 16;
    float xv[16];
    #pragma unroll
    for (int k = 0; k < 4; ++k) {
      float4 v = *(const float4*)(sf + 4 * k);
      xv[4*k+0] = v.x * INVF; xv[4*k+1] = v.y * INVF;
      xv[4*k+2] = v.z * INVF; xv[4*k+3] = v.w * INVF;
    }
    unsigned short qh[8], ql[8];
    #pragma unroll
    for (int kk = 0; kk < 4; ++kk) {
      splitbf(xv[4*h + kk],     qh[kk],   ql[kk]);
      splitbf(xv[8 + 4*h + kk], qh[4+kk], ql[4+kk]);
    }
    uint4 UH = make_uint4((unsigned)qh[0] | ((unsigned)qh[1] << 16),
                          (unsigned)qh[2] | ((unsigned)qh[3] << 16),
                          (unsigned)qh[4] | ((unsigned)qh[5] << 16),
                          (unsigned)qh[6] | ((unsigned)qh[7] << 16));
    uint4 UL = make_uint4((unsigned)ql[0] | ((unsigned)ql[1] << 16),
                          (unsigned)ql[2] | ((unsigned)ql[3] << 16),
                          (unsigned)ql[4] | ((unsigned)ql[5] << 16),
                          (unsigned)ql[6] | ((unsigned)ql[7] << 16));
    if (t == 0) { xaH.q = UH; xaL.q = UL; } else { xbH.q = UH; xbL.q = UL; }
  }

  __syncthreads();

  f32x2 t01a = {0.f,0.f}, t2sa = {0.f,0.f};
  f32x2 t01b = {0.f,0.f}, t2sb = {0.f,0.f};

  #pragma unroll
  for (int jt = 0; jt < 2; ++jt) {
    U yH, yL;
    yH.q = sY[jt * 128 + l];
    yL.q = sY[jt * 128 + 64 + l];
    f32x16 z = {};
    // split-bf16 dot: yl*xh + yh*xl + yh*xh  (error ~2^-17 relative)
    f32x16 c1a = __builtin_amdgcn_mfma_f32_32x32x16_bf16(yL.s, xaH.s, z, 0, 0, 0);
    c1a = __builtin_amdgcn_mfma_f32_32x32x16_bf16(yH.s, xaL.s, c1a, 0, 0, 0);
    c1a = __builtin_amdgcn_mfma_f32_32x32x16_bf16(yH.s, xaH.s, c1a, 0, 0, 0);
    f32x16 c1b = __builtin_amdgcn_mfma_f32_32x32x16_bf16(yL.s, xbH.s, z, 0, 0, 0);
    c1b = __builtin_amdgcn_mfma_f32_32x32x16_bf16(yH.s, xbL.s, c1b, 0, 0, 0);
    c1b = __builtin_amdgcn_mfma_f32_32x32x16_bf16(yH.s, xbH.s, c1b, 0, 0, 0);

    // PV in exact f32: C-row map j = (r&3) + 8(r>>2) + 4h  [HW-verified]
    #pragma unroll
    for (int r = 0; r < 16; ++r) {
      int jl = (r & 3) + 8 * (r >> 2) + (h << 2) + jt * 32;
      float4 tg = tg4s[jl];                   // broadcast (2-way across halves)
      float pa = __builtin_amdgcn_exp2f(c1a[r] + tg.w);
      float pb = __builtin_amdgcn_exp2f(c1b[r] + tg.w);
      f32x2 pa2 = (f32x2){pa, pa}, pb2 = (f32x2){pb, pb};
      f32x2 txy = (f32x2){tg.x, tg.y}, tz1 = (f32x2){tg.z, 1.f};
      t01a = pkfma(pa2, txy, t01a); t2sa = pkfma(pa2, tz1, t2sa);
      t01b = pkfma(pb2, txy, t01b); t2sb = pkfma(pb2, tz1, t2sb);
    }
  }

  // merge complementary j-halves (lane l <-> l^32 share the same i)
  t01a.x += __shfl_xor(t01a.x, 32, 64); t01a.y += __shfl_xor(t01a.y, 32, 64);
  t2sa.x += __shfl_xor(t2sa.x, 32, 64); t2sa.y += __shfl_xor(t2sa.y, 32, 64);
  t01b.x += __shfl_xor(t01b.x, 32, 64); t01b.y += __shfl_xor(t01b.y, 32, 64);
  t2sb.x += __shfl_xor(t2sb.x, 32, 64); t2sb.y += __shfl_xor(t2sb.y, 32, 64);

  if (h == 0) {
    float4* pp = (float4*)partial + (size_t)(b * JC + jc) * NN;
    pp[i0 + il]      = make_float4(t01a.x, t01a.y, t2sa.x, t2sa.y);
    pp[i0 + 32 + il] = make_float4(t01b.x, t01b.y, t2sb.x, t2sb.y);
  }
}

// ---------------------------------------------------------------- combine (one thread per row)
__global__ __launch_bounds__(256) void combine_kernel(
    const float* __restrict__ partial, const float* __restrict__ src_fea,
    const float* __restrict__ src, const float* __restrict__ F_i,
    double* __restrict__ blockpart) {
  int b = blockIdx.x, xb = blockIdx.y, tid = threadIdx.x;
  int i = xb * 256 + tid;
  int g = b * NN + i;

  float S = 0.f, T0 = 0.f, T1 = 0.f, T2 = 0.f;
  #pragma unroll 8
  for (int c = 0; c < JC; ++c) {
    float4 v = ((const float4*)partial)[(size_t)(b * JC + c) * NN + i];
    T0 += v.x; T1 += v.y; T2 += v.z; S += v.w;
  }
  float invS = 1.f / S;
  float y0 = T0 * invS, y1 = T1 * invS, y2 = T2 * invS;

  const float4* sfp = (const float4*)src_fea + (size_t)g * 4;
  float ss = 0.f;
  #pragma unroll
  for (int k = 0; k < 4; ++k) {
    float4 a = sfp[k];
    ss += a.x*a.x + a.y*a.y + a.z*a.z + a.w*a.w;
  }
  float x2 = ss * INV2;
  float w = __builtin_amdgcn_exp2f((F_i[g] * IB2 - x2) * LOG2E
                                   + __builtin_amdgcn_logf(S));

  float px = src[(size_t)g * 3 + 0];
  float py = src[(size_t)g * 3 + 1];
  float pz = src[(size_t)g * 3 + 2];

  double acc[23];
  double wd = (double)w, w2 = wd * wd;
  acc[0]  = wd;
  acc[1]  = wd * px;  acc[2]  = wd * py;  acc[3]  = wd * pz;
  acc[4]  = wd * y0;  acc[5]  = wd * y1;  acc[6]  = wd * y2;
  acc[7]  = w2;
  acc[8]  = w2 * px;  acc[9]  = w2 * py;  acc[10] = w2 * pz;
  acc[11] = w2 * y0;  acc[12] = w2 * y1;  acc[13] = w2 * y2;
  acc[14] = w2 * y0 * px; acc[15] = w2 * y0 * py; acc[16] = w2 * y0 * pz;
  acc[17] = w2 * y1 * px; acc[18] = w2 * y1 * py; acc[19] = w2 * y1 * pz;
  acc[20] = w2 * y2 * px; acc[21] = w2 * y2 * py; acc[22] = w2 * y2 * pz;

  #pragma unroll
  for (int k = 0; k < 23; ++k) {
    #pragma unroll
    for (int off = 32; off > 0; off >>= 1)
      acc[k] += __shfl_down(acc[k], off, 64);
  }
  __shared__ double red[4][23];
  int wave = tid >> 6, lane = tid & 63;
  if (lane == 0) {
    #pragma unroll
    for (int k = 0; k < 23; ++k) red[wave][k] = acc[k];
  }
  __syncthreads();
  if (tid < 23) {
    double s = red[0][tid] + red[1][tid] + red[2][tid] + red[3][tid];
    blockpart[((size_t)b * 16 + xb) * 23 + tid] = s;
  }
}

// ---------------------------------------------------------------- finalize (SVD)
__device__ __forceinline__ double det3(const double M[3][3]) {
  return M[0][0] * (M[1][1] * M[2][2] - M[1][2] * M[2][1])
       - M[0][1] * (M[1][0] * M[2][2] - M[1][2] * M[2][0])
       + M[0][2] * (M[1][0] * M[2][1] - M[1][1] * M[2][0]);
}

__global__ void finalize_kernel(const double* __restrict__ blockpart,
                                float* __restrict__ out) {
  __shared__ double sm[BB][23];
  int tid = threadIdx.x;
  int b = tid >> 6, lane = tid & 63;
  if (lane < 23) {
    double s = 0.0;
    for (int xb = 0; xb < 16; ++xb)
      s += blockpart[((size_t)b * 16 + xb) * 23 + lane];
    sm[b][lane] = s;
  }
  __syncthreads();
  if (lane != 0) return;

  double mo[23];
  #pragma unroll
  for (int k = 0; k < 23; ++k) mo[k] = sm[b][k];

  double sw = mo[0];
  double mux[3] = { mo[1] / sw, mo[2] / sw, mo[3] / sw };
  double muy[3] = { mo[4] / sw, mo[5] / sw, mo[6] / sw };
  double sw2 = mo[7];
  double A[3][3];
  for (int d = 0; d < 3; ++d)
    for (int e = 0; e < 3; ++e)
      A[d][e] = mo[14 + d * 3 + e] - muy[d] * mo[8 + e] - mux[e] * mo[11 + d]
              + sw2 * muy[d] * mux[e];

  double ATA[3][3];
  for (int p = 0; p < 3; ++p)
    for (int q = 0; q < 3; ++q)
      ATA[p][q] = A[0][p] * A[0][q] + A[1][p] * A[1][q] + A[2][p] * A[2][q];

  double V[3][3] = { {1,0,0}, {0,1,0}, {0,0,1} };
  for (int sweep = 0; sweep < 8; ++sweep) {
    for (int pair = 0; pair < 3; ++pair) {
      int p = (pair == 2) ? 1 : 0;
      int q = (pair == 0) ? 1 : 2;
      double apq = ATA[p][q];
      if (fabs(apq) < 1e-300) continue;
      double tau = (ATA[q][q] - ATA[p][p]) / (2.0 * apq);
      double tt = ((tau >= 0.0) ? 1.0 : -1.0) / (fabs(tau) + sqrt(1.0 + tau * tau));
      double c = 1.0 / sqrt(1.0 + tt * tt), sn = tt * c;
      for (int k = 0; k < 3; ++k) {
        double akp = ATA[k][p], akq = ATA[k][q];
        ATA[k][p] = c * akp - sn * akq;
        ATA[k][q] = sn * akp + c * akq;
      }
      for (int k = 0; k < 3; ++k) {
        double apk = ATA[p][k], aqk = ATA[q][k];
        ATA[p][k] = c * apk - sn * aqk;
        ATA[q][k] = sn * apk + c * aqk;
      }
      for (int k = 0; k < 3; ++k) {
        double vkp = V[k][p], vkq = V[k][q];
        V[k][p] = c * vkp - sn * vkq;
        V[k][q] = sn * vkp + c * vkq;
      }
    }
  }

  double U[3][3];
  for (int k = 0; k < 3; ++k) {
    double sv = sqrt(fmax(ATA[k][k], 0.0));
    double u0 = A[0][0] * V[0][k] + A[0][1] * V[1][k] + A[0][2] * V[2][k];
    double u1 = A[1][0] * V[0][k] + A[1][1] * V[1][k] + A[1][2] * V[2][k];
    double u2 = A[2][0] * V[0][k] + A[2][1] * V[1][k] + A[2][2] * V[2][k];
    double inv = (sv > 1e-300) ? 1.0 / sv : 0.0;
    U[0][k] = u0 * inv; U[1][k] = u1 * inv; U[2][k] = u2 * inv;
  }

  double dd = det3(U) * det3(V);
  double R[3][3];
  for (int d = 0; d < 3; ++d)
    for (int e = 0; e < 3; ++e)
      R[d][e] = U[d][0] * V[e][0] + U[d][1] * V[e][1] + U[d][2] * V[e][2];
  R[2][0] *= dd; R[2][1] *= dd; R[2][2] *= dd;

  double tr[3];
  for (int d = 0; d < 3; ++d)
    tr[d] = muy[d] - (R[d][0] * mux[0] + R[d][1] * mux[1] + R[d][2] * mux[2]);

  for (int d = 0; d < 3; ++d)
    for (int e = 0; e < 3; ++e)
      out[b * 9 + d * 3 + e] = (float)R[d][e];
  out[BB * 9 + b * 3 + 0] = (float)tr[0];
  out[BB * 9 + b * 3 + 1] = (float)tr[1];
  out[BB * 9 + b * 3 + 2] = (float)tr[2];
}

// ---------------------------------------------------------------- launch
extern "C" void kernel_launch(void* const* d_in, const int* in_sizes, int n_in,
                              void* d_out, int out_size, void* d_ws, size_t ws_size,
                              hipStream_t stream) {
  const float* src     = (const float*)d_in[0];
  const float* tgt     = (const float*)d_in[1];
  const float* src_fea = (const float*)d_in[2];
  const float* tgt_fea = (const float*)d_in[3];
  const float* F_i     = (const float*)d_in[4];
  const float* G_j     = (const float*)d_in[5];
  float* ws  = (float*)d_ws;
  float* out = (float*)d_out;
  double* blockpart = (double*)(ws + BLK_F);

  prep_kernel<<<BB * MM / 256, 256, 0, stream>>>(tgt_fea, G_j, tgt, ws);
  dim3 grid(NN / 256, JC, BB);   // 16 x 64 x 4 = 4096 blocks
  attn_kernel<<<grid, 256, 0, stream>>>(src_fea, ws, ws + PART_F);
  dim3 cgrid(BB, NN / 256);
  combine_kernel<<<cgrid, 256, 0, stream>>>(ws + PART_F, src_fea, src, F_i, blockpart);
  finalize_kernel<<<1, 256, 0, stream>>>(blockpart, out);
}

// Round 12
// 114.863 us; speedup vs baseline: 1.2020x; 1.1227x over previous
//
#include <hip/hip_runtime.h>
#include <hip/hip_bf16.h>
#include <math.h>

#define BB 4
#define NN 4096
#define MM 4096
#define JC 16           // j-chunks (grid.y); CHUNK = 256 j = 8 MFMA j-tiles
#define CHUNK (MM / JC)
#define TPC (CHUNK / 32) // 8 j-tiles per chunk

#define INVF  70.71067811865475f   // 1/(sqrt(2)*blur)
#define IB2   10000.0f             // 1/blur^2
#define INV2  5000.0f              // INVF^2
#define LOG2E 1.4426950408889634f
#define SCY   (INVF * 2.0f * LOG2E) // yy-side scale (log2 domain)

// ws layout in floats
#define YF_F   0                          // BB*(MM/32)*128 uint4 = 262144 floats (split bf16 A-frags)
#define TG4_F  262144                     // BB*MM float4 = 65536 floats (tgt.xyz, gyl)
#define PART_F 327680                     // BB*JC*NN*4 = 1048576 floats
#define BLK_F  (PART_F + BB * JC * NN * 4) // 64*23 doubles

typedef __attribute__((ext_vector_type(2)))  float f32x2;
typedef __attribute__((ext_vector_type(8)))  short short8v;
typedef __attribute__((ext_vector_type(16))) float f32x16;

static __device__ __forceinline__ unsigned short f2bf(float x) {
  unsigned int u = __builtin_bit_cast(unsigned int, x);
  u += 0x7fffu + ((u >> 16) & 1u);   // RNE
  return (unsigned short)(u >> 16);
}
static __device__ __forceinline__ float bf2f(unsigned short h) {
  unsigned int u = ((unsigned int)h) << 16;
  return __builtin_bit_cast(float, u);
}
// split v into hi+lo bf16 (Ootomo): v ≈ bf2f(h) + bf2f(l), error ~2^-18 |v|
static __device__ __forceinline__ void splitbf(float v, unsigned short& h, unsigned short& l) {
  h = f2bf(v);
  l = f2bf(v - bf2f(h));
}
static __device__ __forceinline__ f32x2 pkfma(f32x2 a, f32x2 b, f32x2 c) {
  f32x2 d;
  asm("v_pk_fma_f32 %0, %1, %2, %3" : "=v"(d) : "v"(a), "v"(b), "v"(c));
  return d;
}

// ---------------------------------------------------------------- prep: split-bf16 A-frags + tgt records
// k-map convention (shared by A and B → permutation-proof):
//   lane(h=l>>5, row=j&31): words 0,1 = feats[4h..4h+3], words 2,3 = feats[8+4h..8+4h+3]
__global__ __launch_bounds__(256) void prep_kernel(
    const float* __restrict__ tgt_fea, const float* __restrict__ G_j,
    const float* __restrict__ tgt, float* __restrict__ ws) {
  int idx = blockIdx.x * 256 + threadIdx.x; // [0, BB*MM)
  int b = idx >> 12, j = idx & (MM - 1);
  const float4* tf = (const float4*)(tgt_fea + (size_t)idx * 16);
  float f[16];
  float ss = 0.f;
  #pragma unroll
  for (int k = 0; k < 4; ++k) {
    float4 v = tf[k];
    f[4*k+0] = v.x; f[4*k+1] = v.y; f[4*k+2] = v.z; f[4*k+3] = v.w;
    ss += v.x*v.x + v.y*v.y + v.z*v.z + v.w*v.w;
  }
  float y2n = ss * INV2;   // ||yy||^2 in nats

  unsigned short vh[16], vl[16];
  #pragma unroll
  for (int k = 0; k < 16; ++k) splitbf(f[k] * SCY, vh[k], vl[k]);

  uint4* base = (uint4*)(ws + YF_F) + ((size_t)b * (MM/32) + (j >> 5)) * 128;
  int ll = j & 31, lh = 32 + (j & 31);
  base[0*64 + ll] = make_uint4(
      (unsigned)vh[0] | ((unsigned)vh[1] << 16), (unsigned)vh[2] | ((unsigned)vh[3] << 16),
      (unsigned)vh[8] | ((unsigned)vh[9] << 16), (unsigned)vh[10] | ((unsigned)vh[11] << 16));
  base[1*64 + ll] = make_uint4(
      (unsigned)vl[0] | ((unsigned)vl[1] << 16), (unsigned)vl[2] | ((unsigned)vl[3] << 16),
      (unsigned)vl[8] | ((unsigned)vl[9] << 16), (unsigned)vl[10] | ((unsigned)vl[11] << 16));
  base[0*64 + lh] = make_uint4(
      (unsigned)vh[4] | ((unsigned)vh[5] << 16), (unsigned)vh[6] | ((unsigned)vh[7] << 16),
      (unsigned)vh[12] | ((unsigned)vh[13] << 16), (unsigned)vh[14] | ((unsigned)vh[15] << 16));
  base[1*64 + lh] = make_uint4(
      (unsigned)vl[4] | ((unsigned)vl[5] << 16), (unsigned)vl[6] | ((unsigned)vl[7] << 16),
      (unsigned)vl[12] | ((unsigned)vl[13] << 16), (unsigned)vl[14] | ((unsigned)vl[15] << 16));

  float gyl = LOG2E * (G_j[idx] * IB2 - y2n);
  ((float4*)(ws + TG4_F))[idx] = make_float4(
      tgt[(size_t)idx*3+0], tgt[(size_t)idx*3+1], tgt[(size_t)idx*3+2], gyl);
}

// ---------------------------------------------------------------- attention (split-bf16 MFMA scores, f32 VALU PV)
__global__ __launch_bounds__(256, 4) void attn_kernel(
    const float* __restrict__ src_fea, const float* __restrict__ ws,
    float* __restrict__ partial) {
  __shared__ uint4  sY[TPC * 128];   // 16 KB: 8 j-tiles x {hi,lo} x 64 lanes
  __shared__ float4 tg4s[CHUNK];     // 4 KB
  int tid = threadIdx.x;
  int w = tid >> 6, l = tid & 63;
  int il = l & 31, h = l >> 5;
  int b = blockIdx.z, jc = blockIdx.y;

  // stage A-frags + tgt records for this chunk
  {
    const uint4* gY = (const uint4*)(ws + YF_F)
                    + ((size_t)b * (MM/32) + jc * TPC) * 128;
    #pragma unroll
    for (int k = 0; k < TPC * 128 / 256; ++k)
      sY[tid + k * 256] = gY[tid + k * 256];
    tg4s[tid] = ((const float4*)(ws + TG4_F))[(size_t)b * MM + jc * CHUNK + tid];
  }

  // B-frags (queries): wave handles 2 i-tiles (64 rows); split-bf16, same k-map
  int i0 = blockIdx.x * 256 + w * 64;
  union U { uint4 q; short8v s; };
  U xaH, xaL, xbH, xbL;
  #pragma unroll
  for (int t = 0; t < 2; ++t) {
    const float* sf = src_fea + ((size_t)b * NN + i0 + t * 32 + il) * 16;
    float xv[16];
    #pragma unroll
    for (int k = 0; k < 4; ++k) {
      float4 v = *(const float4*)(sf + 4 * k);
      xv[4*k+0] = v.x * INVF; xv[4*k+1] = v.y * INVF;
      xv[4*k+2] = v.z * INVF; xv[4*k+3] = v.w * INVF;
    }
    unsigned short qh[8], ql[8];
    #pragma unroll
    for (int kk = 0; kk < 4; ++kk) {
      splitbf(xv[4*h + kk],     qh[kk],   ql[kk]);
      splitbf(xv[8 + 4*h + kk], qh[4+kk], ql[4+kk]);
    }
    uint4 UH = make_uint4((unsigned)qh[0] | ((unsigned)qh[1] << 16),
                          (unsigned)qh[2] | ((unsigned)qh[3] << 16),
                          (unsigned)qh[4] | ((unsigned)qh[5] << 16),
                          (unsigned)qh[6] | ((unsigned)qh[7] << 16));
    uint4 UL = make_uint4((unsigned)ql[0] | ((unsigned)ql[1] << 16),
                          (unsigned)ql[2] | ((unsigned)ql[3] << 16),
                          (unsigned)ql[4] | ((unsigned)ql[5] << 16),
                          (unsigned)ql[6] | ((unsigned)ql[7] << 16));
    if (t == 0) { xaH.q = UH; xaL.q = UL; } else { xbH.q = UH; xbL.q = UL; }
  }

  __syncthreads();

  f32x2 t01a = {0.f,0.f}, t2sa = {0.f,0.f};
  f32x2 t01b = {0.f,0.f}, t2sb = {0.f,0.f};

  #pragma unroll 2
  for (int jt = 0; jt < TPC; ++jt) {
    U yH, yL;
    yH.q = sY[jt * 128 + l];
    yL.q = sY[jt * 128 + 64 + l];
    f32x16 z = {};
    // split-bf16 dot: yl*xh + yh*xl + yh*xh  (error ~2^-17 relative)
    f32x16 c1a = __builtin_amdgcn_mfma_f32_32x32x16_bf16(yL.s, xaH.s, z, 0, 0, 0);
    c1a = __builtin_amdgcn_mfma_f32_32x32x16_bf16(yH.s, xaL.s, c1a, 0, 0, 0);
    c1a = __builtin_amdgcn_mfma_f32_32x32x16_bf16(yH.s, xaH.s, c1a, 0, 0, 0);
    f32x16 c1b = __builtin_amdgcn_mfma_f32_32x32x16_bf16(yL.s, xbH.s, z, 0, 0, 0);
    c1b = __builtin_amdgcn_mfma_f32_32x32x16_bf16(yH.s, xbL.s, c1b, 0, 0, 0);
    c1b = __builtin_amdgcn_mfma_f32_32x32x16_bf16(yH.s, xbH.s, c1b, 0, 0, 0);

    // PV in exact f32: C-row map j = (r&3) + 8(r>>2) + 4h  [HW-verified]
    #pragma unroll
    for (int r = 0; r < 16; ++r) {
      int jl = (r & 3) + 8 * (r >> 2) + (h << 2) + jt * 32;
      float4 tg = tg4s[jl];                   // broadcast read
      float pa = __builtin_amdgcn_exp2f(c1a[r] + tg.w);
      float pb = __builtin_amdgcn_exp2f(c1b[r] + tg.w);
      f32x2 pa2 = (f32x2){pa, pa}, pb2 = (f32x2){pb, pb};
      f32x2 txy = (f32x2){tg.x, tg.y}, tz1 = (f32x2){tg.z, 1.f};
      t01a = pkfma(pa2, txy, t01a); t2sa = pkfma(pa2, tz1, t2sa);
      t01b = pkfma(pb2, txy, t01b); t2sb = pkfma(pb2, tz1, t2sb);
    }
  }

  // merge complementary j-halves (lane l <-> l^32 share the same i)
  t01a.x += __shfl_xor(t01a.x, 32, 64); t01a.y += __shfl_xor(t01a.y, 32, 64);
  t2sa.x += __shfl_xor(t2sa.x, 32, 64); t2sa.y += __shfl_xor(t2sa.y, 32, 64);
  t01b.x += __shfl_xor(t01b.x, 32, 64); t01b.y += __shfl_xor(t01b.y, 32, 64);
  t2sb.x += __shfl_xor(t2sb.x, 32, 64); t2sb.y += __shfl_xor(t2sb.y, 32, 64);

  if (h == 0) {
    float4* pp = (float4*)partial + (size_t)(b * JC + jc) * NN;
    pp[i0 + il]      = make_float4(t01a.x, t01a.y, t2sa.x, t2sa.y);
    pp[i0 + 32 + il] = make_float4(t01b.x, t01b.y, t2sb.x, t2sb.y);
  }
}

// ---------------------------------------------------------------- combine (one thread per row)
__global__ __launch_bounds__(256) void combine_kernel(
    const float* __restrict__ partial, const float* __restrict__ src_fea,
    const float* __restrict__ src, const float* __restrict__ F_i,
    double* __restrict__ blockpart) {
  int b = blockIdx.x, xb = blockIdx.y, tid = threadIdx.x;
  int i = xb * 256 + tid;
  int g = b * NN + i;

  float S = 0.f, T0 = 0.f, T1 = 0.f, T2 = 0.f;
  #pragma unroll
  for (int c = 0; c < JC; ++c) {
    float4 v = ((const float4*)partial)[(size_t)(b * JC + c) * NN + i];
    T0 += v.x; T1 += v.y; T2 += v.z; S += v.w;
  }
  float invS = 1.f / S;
  float y0 = T0 * invS, y1 = T1 * invS, y2 = T2 * invS;

  const float4* sfp = (const float4*)src_fea + (size_t)g * 4;
  float ss = 0.f;
  #pragma unroll
  for (int k = 0; k < 4; ++k) {
    float4 a = sfp[k];
    ss += a.x*a.x + a.y*a.y + a.z*a.z + a.w*a.w;
  }
  float x2 = ss * INV2;
  float w = __builtin_amdgcn_exp2f((F_i[g] * IB2 - x2) * LOG2E
                                   + __builtin_amdgcn_logf(S));

  float px = src[(size_t)g * 3 + 0];
  float py = src[(size_t)g * 3 + 1];
  float pz = src[(size_t)g * 3 + 2];

  double acc[23];
  double wd = (double)w, w2 = wd * wd;
  acc[0]  = wd;
  acc[1]  = wd * px;  acc[2]  = wd * py;  acc[3]  = wd * pz;
  acc[4]  = wd * y0;  acc[5]  = wd * y1;  acc[6]  = wd * y2;
  acc[7]  = w2;
  acc[8]  = w2 * px;  acc[9]  = w2 * py;  acc[10] = w2 * pz;
  acc[11] = w2 * y0;  acc[12] = w2 * y1;  acc[13] = w2 * y2;
  acc[14] = w2 * y0 * px; acc[15] = w2 * y0 * py; acc[16] = w2 * y0 * pz;
  acc[17] = w2 * y1 * px; acc[18] = w2 * y1 * py; acc[19] = w2 * y1 * pz;
  acc[20] = w2 * y2 * px; acc[21] = w2 * y2 * py; acc[22] = w2 * y2 * pz;

  #pragma unroll
  for (int k = 0; k < 23; ++k) {
    #pragma unroll
    for (int off = 32; off > 0; off >>= 1)
      acc[k] += __shfl_down(acc[k], off, 64);
  }
  __shared__ double red[4][23];
  int wave = tid >> 6, lane = tid & 63;
  if (lane == 0) {
    #pragma unroll
    for (int k = 0; k < 23; ++k) red[wave][k] = acc[k];
  }
  __syncthreads();
  if (tid < 23) {
    double s = red[0][tid] + red[1][tid] + red[2][tid] + red[3][tid];
    blockpart[((size_t)b * 16 + xb) * 23 + tid] = s;
  }
}

// ---------------------------------------------------------------- finalize (SVD)
__device__ __forceinline__ double det3(const double M[3][3]) {
  return M[0][0] * (M[1][1] * M[2][2] - M[1][2] * M[2][1])
       - M[0][1] * (M[1][0] * M[2][2] - M[1][2] * M[2][0])
       + M[0][2] * (M[1][0] * M[2][1] - M[1][1] * M[2][0]);
}

__global__ void finalize_kernel(const double* __restrict__ blockpart,
                                float* __restrict__ out) {
  __shared__ double sm[BB][23];
  int tid = threadIdx.x;
  int b = tid >> 6, lane = tid & 63;
  if (lane < 23) {
    double s = 0.0;
    for (int xb = 0; xb < 16; ++xb)
      s += blockpart[((size_t)b * 16 + xb) * 23 + lane];
    sm[b][lane] = s;
  }
  __syncthreads();
  if (lane != 0) return;

  double mo[23];
  #pragma unroll
  for (int k = 0; k < 23; ++k) mo[k] = sm[b][k];

  double sw = mo[0];
  double mux[3] = { mo[1] / sw, mo[2] / sw, mo[3] / sw };
  double muy[3] = { mo[4] / sw, mo[5] / sw, mo[6] / sw };
  double sw2 = mo[7];
  double A[3][3];
  for (int d = 0; d < 3; ++d)
    for (int e = 0; e < 3; ++e)
      A[d][e] = mo[14 + d * 3 + e] - muy[d] * mo[8 + e] - mux[e] * mo[11 + d]
              + sw2 * muy[d] * mux[e];

  double ATA[3][3];
  for (int p = 0; p < 3; ++p)
    for (int q = 0; q < 3; ++q)
      ATA[p][q] = A[0][p] * A[0][q] + A[1][p] * A[1][q] + A[2][p] * A[2][q];

  double V[3][3] = { {1,0,0}, {0,1,0}, {0,0,1} };
  for (int sweep = 0; sweep < 8; ++sweep) {
    for (int pair = 0; pair < 3; ++pair) {
      int p = (pair == 2) ? 1 : 0;
      int q = (pair == 0) ? 1 : 2;
      double apq = ATA[p][q];
      if (fabs(apq) < 1e-300) continue;
      double tau = (ATA[q][q] - ATA[p][p]) / (2.0 * apq);
      double tt = ((tau >= 0.0) ? 1.0 : -1.0) / (fabs(tau) + sqrt(1.0 + tau * tau));
      double c = 1.0 / sqrt(1.0 + tt * tt), sn = tt * c;
      for (int k = 0; k < 3; ++k) {
        double akp = ATA[k][p], akq = ATA[k][q];
        ATA[k][p] = c * akp - sn * akq;
        ATA[k][q] = sn * akp + c * akq;
      }
      for (int k = 0; k < 3; ++k) {
        double apk = ATA[p][k], aqk = ATA[q][k];
        ATA[p][k] = c * apk - sn * aqk;
        ATA[q][k] = sn * apk + c * aqk;
      }
      for (int k = 0; k < 3; ++k) {
        double vkp = V[k][p], vkq = V[k][q];
        V[k][p] = c * vkp - sn * vkq;
        V[k][q] = sn * vkp + c * vkq;
      }
    }
  }

  double U[3][3];
  for (int k = 0; k < 3; ++k) {
    double sv = sqrt(fmax(ATA[k][k], 0.0));
    double u0 = A[0][0] * V[0][k] + A[0][1] * V[1][k] + A[0][2] * V[2][k];
    double u1 = A[1][0] * V[0][k] + A[1][1] * V[1][k] + A[1][2] * V[2][k];
    double u2 = A[2][0] * V[0][k] + A[2][1] * V[1][k] + A[2][2] * V[2][k];
    double inv = (sv > 1e-300) ? 1.0 / sv : 0.0;
    U[0][k] = u0 * inv; U[1][k] = u1 * inv; U[2][k] = u2 * inv;
  }

  double dd = det3(U) * det3(V);
  double R[3][3];
  for (int d = 0; d < 3; ++d)
    for (int e = 0; e < 3; ++e)
      R[d][e] = U[d][0] * V[e][0] + U[d][1] * V[e][1] + U[d][2] * V[e][2];
  R[2][0] *= dd; R[2][1] *= dd; R[2][2] *= dd;

  double tr[3];
  for (int d = 0; d < 3; ++d)
    tr[d] = muy[d] - (R[d][0] * mux[0] + R[d][1] * mux[1] + R[d][2] * mux[2]);

  for (int d = 0; d < 3; ++d)
    for (int e = 0; e < 3; ++e)
      out[b * 9 + d * 3 + e] = (float)R[d][e];
  out[BB * 9 + b * 3 + 0] = (float)tr[0];
  out[BB * 9 + b * 3 + 1] = (float)tr[1];
  out[BB * 9 + b * 3 + 2] = (float)tr[2];
}

// ---------------------------------------------------------------- launch
extern "C" void kernel_launch(void* const* d_in, const int* in_sizes, int n_in,
                              void* d_out, int out_size, void* d_ws, size_t ws_size,
                              hipStream_t stream) {
  const float* src     = (const float*)d_in[0];
  const float* tgt     = (const float*)d_in[1];
  const float* src_fea = (const float*)d_in[2];
  const float* tgt_fea = (const float*)d_in[3];
  const float* F_i     = (const float*)d_in[4];
  const float* G_j     = (const float*)d_in[5];
  float* ws  = (float*)d_ws;
  float* out = (float*)d_out;
  double* blockpart = (double*)(ws + BLK_F);

  prep_kernel<<<BB * MM / 256, 256, 0, stream>>>(tgt_fea, G_j, tgt, ws);
  dim3 grid(NN / 256, JC, BB);   // 16 x 16 x 4 = 1024 blocks
  attn_kernel<<<grid, 256, 0, stream>>>(src_fea, ws, ws + PART_F);
  dim3 cgrid(BB, NN / 256);
  combine_kernel<<<cgrid, 256, 0, stream>>>(ws + PART_F, src_fea, src, F_i, blockpart);
  finalize_kernel<<<1, 256, 0, stream>>>(blockpart, out);
}